// Round 9
// baseline (348.601 us; speedup 1.0000x reference)
//
#include <hip/hip_runtime.h>
#include <hip/hip_fp16.h>

namespace {

constexpr int kB = 128, kI = 1152, kD = 8, kN = 32, kE = 16;
constexpr int kIC = 8;               // input capsules per block
constexpr int kNG = kI / kIC;        // 144 i-groups
constexpr size_t kPartBytes = (size_t)kNG * kN * kB * kE * 2;  // 18.9 MB fp16
constexpr size_t kVsumBytes = (size_t)kB * kN * kE * 4;        // 256 KB f32

typedef _Float16 h2v __attribute__((ext_vector_type(2)));

__device__ __forceinline__ float fdot2(__half2 a, __half2 b, float c) {
  return __builtin_amdgcn_fdot2(__builtin_bit_cast(h2v, a),
                                __builtin_bit_cast(h2v, b), c, false);
}

union I4H { int4 v; __half2 h[4]; };

// Stage-write: wst (8 x dwordx4 of W f32, coalesced-read) -> fp16 LDS in
// [il][n][ep][d] half2 layout (d contiguous per (n,ep) so the compute read
// is 2x ds_read_b128, 8 distinct 16B lines x 8-lane broadcast = conflict-free).
__device__ __forceinline__ void stage_write(__half2* dst, const float4* wst, int t) {
#pragma unroll
  for (int j = 0; j < 8; ++j) {
    const int fidx = (j * 256 + t) * 4;          // f32 index within 2-i slice
    const int il = fidx >> 12, rem = fidx & 4095;
    const int n = rem >> 7, d = (rem >> 4) & 7, ep0 = (rem & 15) >> 1;
    __half2* p = dst + il * 2048 + n * 64 + d;
    p[ep0 * 8]       = __floats2half2_rn(wst[j].x, wst[j].y);
    p[(ep0 + 1) * 8] = __floats2half2_rn(wst[j].z, wst[j].w);
  }
}

// Routing pass, transposed lanes: lane = (ep 8) x (bl 8); n in REGISTERS.
// Per (b,i): uh[n] via 8 hfma2 from LDS-broadcast W; logit = fdot2 + 3-step
// ep-butterfly; softmax register-local (no max-sub; bounded logits); s[n]
// accumulated over the block's 8 i; one partial store per (b,n).
template<int PASS>
__global__ __launch_bounds__(256, 2)
void caps_pass(const float* __restrict__ x, const float* __restrict__ W,
               const float* __restrict__ bias, const __half* __restrict__ vsh,
               __half* __restrict__ part)
{
  __shared__ __align__(16) __half2 wl[2][2][kN * 8 * 8];  // dbuf x 2i x 2048 h2 = 32 KB

  const int g  = (int)blockIdx.x;
  const int g0 = g * kIC;
  const int b0 = (int)blockIdx.y * 32;
  const int t  = (int)threadIdx.x;
  const int wv = t >> 6, L = t & 63;
  const int ep = L >> 3, bl = L & 7;
  const int b  = b0 + wv * 8 + bl;

  // v[b] for my e-pair, hoisted once (L2-hot, 32 x 4B)
  __half2 vr[kN];
  if (PASS > 0) {
#pragma unroll
    for (int n = 0; n < kN; ++n)
      vr[n] = *reinterpret_cast<const __half2*>(
          vsh + ((size_t)b * kN + n) * kE + ep * 2);
  }

  __half2 s[kN];
#pragma unroll
  for (int n = 0; n < kN; ++n) s[n] = __half2half2(__float2half(0.f));

  float4 wst[8];
  {  // prologue: stage q=0
    const float* wsrc = W + (size_t)g0 * (kN * kD * kE);
#pragma unroll
    for (int j = 0; j < 8; ++j)
      wst[j] = *reinterpret_cast<const float4*>(wsrc + (size_t)(j * 256 + t) * 4);
    stage_write(&wl[0][0][0], wst, t);
  }
  __syncthreads();

#pragma unroll 1
  for (int q = 0; q < 4; ++q) {
    if (q < 3) {  // issue next stage's global loads early
      const float* wsrc = W + (size_t)(g0 + (q + 1) * 2) * (kN * kD * kE);
#pragma unroll
      for (int j = 0; j < 8; ++j)
        wst[j] = *reinterpret_cast<const float4*>(wsrc + (size_t)(j * 256 + t) * 4);
    }
#pragma unroll 1
    for (int il = 0; il < 2; ++il) {
      const int i = g0 + q * 2 + il;
      // x row -> 8 dup-half2
      const float* xp = x + ((size_t)b * kI + i) * kD;
      const float4 xa = *reinterpret_cast<const float4*>(xp);
      const float4 xb = *reinterpret_cast<const float4*>(xp + 4);
      __half2 xd[8];
      xd[0] = __half2half2(__float2half_rn(xa.x));
      xd[1] = __half2half2(__float2half_rn(xa.y));
      xd[2] = __half2half2(__float2half_rn(xa.z));
      xd[3] = __half2half2(__float2half_rn(xa.w));
      xd[4] = __half2half2(__float2half_rn(xb.x));
      xd[5] = __half2half2(__float2half_rn(xb.y));
      xd[6] = __half2half2(__float2half_rn(xb.z));
      xd[7] = __half2half2(__float2half_rn(xb.w));

      const __half2* wbase = &wl[q & 1][il][0];
      __half2 uh[kN];
      float lg[kN];
#pragma unroll
      for (int n = 0; n < kN; ++n) {
        const __half2* wp = wbase + n * 64 + ep * 8;
        I4H wa, wb2;
        wa.v  = *reinterpret_cast<const int4*>(wp);      // d 0..3
        wb2.v = *reinterpret_cast<const int4*>(wp + 4);  // d 4..7
        __half2 u = __hmul2(xd[0], wa.h[0]);
        u = __hfma2(xd[1], wa.h[1], u);
        u = __hfma2(xd[2], wa.h[2], u);
        u = __hfma2(xd[3], wa.h[3], u);
        u = __hfma2(xd[4], wb2.h[0], u);
        u = __hfma2(xd[5], wb2.h[1], u);
        u = __hfma2(xd[6], wb2.h[2], u);
        u = __hfma2(xd[7], wb2.h[3], u);
        uh[n] = u;
        const float bn = bias[(size_t)i * kN + n];
        lg[n] = (PASS > 0) ? fdot2(u, vr[n], bn) : bn;
      }
      if (PASS > 0) {  // sum 16 e across 8 ep-lanes: 3 butterfly rounds, 32-way ILP
#pragma unroll
        for (int n = 0; n < kN; ++n) lg[n] += __shfl_xor(lg[n], 8, 64);
#pragma unroll
        for (int n = 0; n < kN; ++n) lg[n] += __shfl_xor(lg[n], 16, 64);
#pragma unroll
        for (int n = 0; n < kN; ++n) lg[n] += __shfl_xor(lg[n], 32, 64);
      }
      // register softmax over n (no max-sub: |logit| <~ 72, exp safe in f32)
#pragma unroll
      for (int n = 0; n < kN; ++n) lg[n] = __expf(lg[n]);
      float tt[16];
#pragma unroll
      for (int k = 0; k < 16; ++k) tt[k] = lg[k] + lg[k + 16];
#pragma unroll
      for (int k = 0; k < 8; ++k) tt[k] += tt[k + 8];
#pragma unroll
      for (int k = 0; k < 4; ++k) tt[k] += tt[k + 4];
      const float rd = __builtin_amdgcn_rcpf((tt[0] + tt[1]) + (tt[2] + tt[3]));
#pragma unroll
      for (int n = 0; n < kN; ++n) {
        const __half2 c2 = __half2half2(__float2half_rn(lg[n] * rd));
        s[n] = __hfma2(c2, uh[n], s[n]);
      }
    }
    if (q < 3) {
      __syncthreads();  // all waves done reading buf[(q+1)&1]
      stage_write(&wl[(q + 1) & 1][0][0], wst, t);
      __syncthreads();
    }
  }

  // partial store: part[g][n][b][e] -> per wave-store 256 B contiguous
#pragma unroll
  for (int n = 0; n < kN; ++n)
    *reinterpret_cast<__half2*>(
        part + (((size_t)g * kN + n) * kB + b) * kE + ep * 2) = s[n];
}

// Fused reduce(144 groups) + squash. Block = 128 thr covers (b, 16 n).
// MODE 0: vsum=v,vsh=v; 1: vsum+=v,vsh=vsum; 2: out=v.
template<int MODE>
__global__ __launch_bounds__(128)
void caps_reduce(const __half* __restrict__ part, float* __restrict__ vsum,
                 __half* __restrict__ vsh, float* __restrict__ out)
{
  const int b  = (int)blockIdx.x;
  const int nh = (int)blockIdx.y;
  const int t  = (int)threadIdx.x;
  const int n  = nh * 16 + (t >> 3), ep = t & 7;
  const size_t base = ((size_t)n * kB + b) * kE + ep * 2;
  constexpr size_t gstr = (size_t)kN * kB * kE;   // halves per g-slab
  float ax = 0.f, ay = 0.f;
#pragma unroll 4
  for (int gg = 0; gg < kNG; ++gg) {
    float2 f = __half22float2(
        *reinterpret_cast<const __half2*>(part + (size_t)gg * gstr + base));
    ax += f.x; ay += f.y;
  }
  float s2 = ax * ax + ay * ay;
  s2 += __shfl_xor(s2, 1, 64);
  s2 += __shfl_xor(s2, 2, 64);
  s2 += __shfl_xor(s2, 4, 64);
  const float sc = (s2 / (1.f + s2)) * rsqrtf(fmaxf(s2, 1e-30f));
  float vx = ax * sc, vy = ay * sc;
  const size_t o = ((size_t)b * kN + n) * kE + ep * 2;
  if (MODE == 2) {
    *reinterpret_cast<float2*>(out + o) = make_float2(vx, vy);
  } else {
    if (MODE == 1) {
      float2 old = *reinterpret_cast<const float2*>(vsum + o);
      vx += old.x; vy += old.y;
    }
    *reinterpret_cast<float2*>(vsum + o) = make_float2(vx, vy);
    *reinterpret_cast<__half2*>(vsh + o) = __floats2half2_rn(vx, vy);
  }
}

}  // namespace

extern "C" void kernel_launch(void* const* d_in, const int* in_sizes, int n_in,
                              void* d_out, int out_size, void* d_ws, size_t ws_size,
                              hipStream_t stream) {
  (void)in_sizes; (void)n_in; (void)out_size; (void)ws_size;
  const float* x    = reinterpret_cast<const float*>(d_in[0]);
  const float* W    = reinterpret_cast<const float*>(d_in[1]);
  const float* bias = reinterpret_cast<const float*>(d_in[2]);
  float* out = reinterpret_cast<float*>(d_out);

  char* ws = reinterpret_cast<char*>(d_ws);
  __half* part = reinterpret_cast<__half*>(ws);
  float*  vsum = reinterpret_cast<float*>(ws + kPartBytes);
  __half* vsh  = reinterpret_cast<__half*>(ws + kPartBytes + kVsumBytes);

  dim3 pg(kNG, kB / 32), pb(256);   // 144 x 4 = 576 blocks
  dim3 rg(kB, 2), rb(128);          // 256 blocks

  // iter 0: c = softmax(bias) (b-independent); v0 -> vsum/vsh
  caps_pass<0><<<pg, pb, 0, stream>>>(x, W, bias, vsh, part);
  caps_reduce<0><<<rg, rb, 0, stream>>>(part, vsum, vsh, out);
  // iter 1: logits = bias + <u_hat, v0>
  caps_pass<1><<<pg, pb, 0, stream>>>(x, W, bias, vsh, part);
  caps_reduce<1><<<rg, rb, 0, stream>>>(part, vsum, vsh, out);
  // iter 2: logits = bias + <u_hat, v0+v1>; out = squash(s)
  caps_pass<1><<<pg, pb, 0, stream>>>(x, W, bias, vsh, part);
  caps_reduce<2><<<rg, rb, 0, stream>>>(part, vsum, vsh, out);
}

// Round 10
// 267.318 us; speedup vs baseline: 1.3041x; 1.3041x over previous
//
#include <hip/hip_runtime.h>
#include <hip/hip_fp16.h>

namespace {

constexpr int kB = 128, kI = 1152, kD = 8, kN = 32, kE = 16;
constexpr int kIC1 = 4,  kNC1 = kI / kIC1;   // K1: 288 i-chunks
constexpr int kIC3 = 8,  kNC3 = kI / kIC3;   // K3: 144 i-chunks (= partial slabs)

// workspace layout (bytes); lg(f32) and partials(fp16) are the SAME region A
// (lg is dead after K2 consumes it; K3 then writes partials there).
constexpr size_t kABytes    = (size_t)kB * kI * kN * 4;  // 18,874,368
constexpr size_t kCBytes    = (size_t)kB * kI * kN * 2;  //  9,437,184
constexpr size_t kWhBytes   = (size_t)kI * kD * 64 * 16; //  9,437,184
constexpr size_t kXhBytes   = (size_t)kB * kI * kD * 2;  //  2,359,296
constexpr size_t kVsumBytes = (size_t)kB * kN * kE * 4;  //    262,144

typedef _Float16 h2v __attribute__((ext_vector_type(2)));
__device__ __forceinline__ float fdot2(__half2 a, __half2 b, float c) {
  return __builtin_amdgcn_fdot2(__builtin_bit_cast(h2v, a),
                                __builtin_bit_cast(h2v, b), c, false);
}
union I4H { int4 v; __half2 h[4]; };
union I2H { int2 v; __half2 h[2]; };
__device__ __forceinline__ __half2 dl(__half2 v) { return __half2half2(__low2half(v)); }
__device__ __forceinline__ __half2 dh(__half2 v) { return __half2half2(__high2half(v)); }

// K0a: W f32 [i][n][d][e] -> Wh fp16, int4-per-lane layout:
// int4 index = (i*8+d)*64 + eh*32 + n ; h[q] = e-pair (eh*8+2q, +1).
// Reads fully coalesced; writes 8B scattered (one-time cost).
__global__ __launch_bounds__(256)
void k0_w(const float* __restrict__ W, __half2* __restrict__ Whh2) {
  const int t = (int)blockIdx.x * 256 + (int)threadIdx.x;   // float4 id
  const float4 w4 = reinterpret_cast<const float4*>(W)[t];
  const int f = t * 4;
  const int e0 = f & 15, d = (f >> 4) & 7, n = (f >> 7) & 31, i = f >> 12;
  const int eh = e0 >> 3, q0 = (e0 & 7) >> 1;   // q0 in {0,2}
  I2H o; o.h[0] = __floats2half2_rn(w4.x, w4.y); o.h[1] = __floats2half2_rn(w4.z, w4.w);
  *reinterpret_cast<int2*>(Whh2 + ((size_t)((i * kD + d) * 64 + eh * 32 + n)) * 4 + q0) = o.v;
}

// K0b: x f32 [b][i][d] -> fp16 16B rows (row r = b*kI + i)
__global__ __launch_bounds__(256)
void k0_x(const float* __restrict__ x, int4* __restrict__ xh4) {
  const int r = (int)blockIdx.x * 256 + (int)threadIdx.x;   // 147,456 rows
  const float4* p = reinterpret_cast<const float4*>(x + (size_t)r * 8);
  const float4 a = p[0], b = p[1];
  I4H o;
  o.h[0] = __floats2half2_rn(a.x, a.y); o.h[1] = __floats2half2_rn(a.z, a.w);
  o.h[2] = __floats2half2_rn(b.x, b.y); o.h[3] = __floats2half2_rn(b.z, b.w);
  xh4[r] = o.v;
}

// K1: lg[b,i,n] = <u_hat(b,i,n,:), v(b,n,:)>   (bias added in K2).
// Wave = (eh 2, n 32); thread loops 8 b; W = 8 transient int4 per i (low
// pressure -> no remat incentive). No LDS.
__global__ __launch_bounds__(256)
void k1_logit(const int4* __restrict__ Wh4, const int4* __restrict__ xh4,
              const __half* __restrict__ vsh, float* __restrict__ lgf) {
  const int i0 = (int)blockIdx.x * kIC1;
  const int t = (int)threadIdx.x, w = t >> 6, L = t & 63;
  const int eh = L >> 5, n = L & 31;
  const int b0 = (int)blockIdx.y * 32 + w * 8;
  I4H vq[8];
#pragma unroll
  for (int bb = 0; bb < 8; ++bb)
    vq[bb].v = *reinterpret_cast<const int4*>(
        vsh + ((size_t)(b0 + bb) * kN + n) * kE + eh * 8);
#pragma unroll 1
  for (int ii = 0; ii < kIC1; ++ii) {
    const int i = i0 + ii;
    I4H wd[8];
#pragma unroll
    for (int d = 0; d < 8; ++d) wd[d].v = Wh4[(size_t)(i * kD + d) * 64 + L];
#pragma unroll
    for (int bb = 0; bb < 8; ++bb) {
      const int b = b0 + bb;
      I4H xv; xv.v = xh4[(size_t)b * kI + i];
      float lg = 0.f;
#pragma unroll
      for (int q = 0; q < 4; ++q) {
        __half2 u = __hmul2(dl(xv.h[0]), wd[0].h[q]);
        u = __hfma2(dh(xv.h[0]), wd[1].h[q], u);
        u = __hfma2(dl(xv.h[1]), wd[2].h[q], u);
        u = __hfma2(dh(xv.h[1]), wd[3].h[q], u);
        u = __hfma2(dl(xv.h[2]), wd[4].h[q], u);
        u = __hfma2(dh(xv.h[2]), wd[5].h[q], u);
        u = __hfma2(dl(xv.h[3]), wd[6].h[q], u);
        u = __hfma2(dh(xv.h[3]), wd[7].h[q], u);
        lg = fdot2(u, vq[bb].h[q], lg);
      }
      lg += __shfl_xor(lg, 32, 64);             // add the other e-octet
      if (eh == 0) lgf[((size_t)b * kI + i) * kN + n] = lg;
    }
  }
}

// K2: c[b,i,:] = softmax(bias[i,:] + lg[b,i,:]) — register-local over 32
// contiguous n (zero cross-lane). No max-sub (|logits| small, exp safe in f32).
template<int WITH_LG>
__global__ __launch_bounds__(192)
void k2_softmax(const float* __restrict__ lgf, const float* __restrict__ bias,
                __half* __restrict__ c) {
  const int i = (int)blockIdx.x * 192 + (int)threadIdx.x;   // 6*192 = 1152
  const int b = (int)blockIdx.y;
  const float4* bp = reinterpret_cast<const float4*>(bias + (size_t)i * kN);
  const float4* lp = reinterpret_cast<const float4*>(lgf + ((size_t)b * kI + i) * kN);
  float e_[kN];
#pragma unroll
  for (int j = 0; j < 8; ++j) {
    float4 bv = bp[j];
    if (WITH_LG) { const float4 lv = lp[j];
      bv.x += lv.x; bv.y += lv.y; bv.z += lv.z; bv.w += lv.w; }
    e_[4 * j + 0] = __expf(bv.x); e_[4 * j + 1] = __expf(bv.y);
    e_[4 * j + 2] = __expf(bv.z); e_[4 * j + 3] = __expf(bv.w);
  }
  float s = 0.f;
#pragma unroll
  for (int n = 0; n < kN; ++n) s += e_[n];
  const float r = __builtin_amdgcn_rcpf(s);
  int4* cp = reinterpret_cast<int4*>(c + ((size_t)b * kI + i) * kN);
#pragma unroll
  for (int k = 0; k < 4; ++k) {
    I4H o;
#pragma unroll
    for (int q = 0; q < 4; ++q)
      o.h[q] = __floats2half2_rn(e_[8 * k + 2 * q] * r, e_[8 * k + 2 * q + 1] * r);
    cp[k] = o.v;
  }
}

// K3: partial s[chunk][b][n][e] = sum_{i in chunk} c[b,i,n] * u_hat(b,i,n,e)
__global__ __launch_bounds__(256)
void k3_accum(const int4* __restrict__ Wh4, const int4* __restrict__ xh4,
              const __half* __restrict__ c, __half* __restrict__ part) {
  const int chunk = (int)blockIdx.x;
  const int i0 = chunk * kIC3;
  const int t = (int)threadIdx.x, w = t >> 6, L = t & 63;
  const int eh = L >> 5, n = L & 31;
  const int b0 = (int)blockIdx.y * 32 + w * 8;
  __half2 s[8][4];
#pragma unroll
  for (int bb = 0; bb < 8; ++bb)
#pragma unroll
    for (int q = 0; q < 4; ++q) s[bb][q] = __half2half2(__float2half(0.f));
#pragma unroll 1
  for (int ii = 0; ii < kIC3; ++ii) {
    const int i = i0 + ii;
    I4H wd[8];
#pragma unroll
    for (int d = 0; d < 8; ++d) wd[d].v = Wh4[(size_t)(i * kD + d) * 64 + L];
#pragma unroll
    for (int bb = 0; bb < 8; ++bb) {
      const int b = b0 + bb;
      I4H xv; xv.v = xh4[(size_t)b * kI + i];
      const __half2 c2 = __half2half2(c[((size_t)b * kI + i) * kN + n]);
#pragma unroll
      for (int q = 0; q < 4; ++q) {
        __half2 u = __hmul2(dl(xv.h[0]), wd[0].h[q]);
        u = __hfma2(dh(xv.h[0]), wd[1].h[q], u);
        u = __hfma2(dl(xv.h[1]), wd[2].h[q], u);
        u = __hfma2(dh(xv.h[1]), wd[3].h[q], u);
        u = __hfma2(dl(xv.h[2]), wd[4].h[q], u);
        u = __hfma2(dh(xv.h[2]), wd[5].h[q], u);
        u = __hfma2(dl(xv.h[3]), wd[6].h[q], u);
        u = __hfma2(dh(xv.h[3]), wd[7].h[q], u);
        s[bb][q] = __hfma2(c2, u, s[bb][q]);
      }
    }
  }
#pragma unroll
  for (int bb = 0; bb < 8; ++bb) {
    I4H o;
#pragma unroll
    for (int q = 0; q < 4; ++q) o.h[q] = s[bb][q];
    *reinterpret_cast<int4*>(
        part + (((size_t)chunk * kB + b0 + bb) * kN + n) * kE + eh * 8) = o.v;
  }
}

// K4: sum 144 slabs, squash. MODE 0: vsum=v,vsh=v; 1: vsum+=v,vsh=vsum; 2: out=v.
template<int MODE>
__global__ __launch_bounds__(256)
void k4_reduce(const __half* __restrict__ part, float* __restrict__ vsum,
               __half* __restrict__ vsh, float* __restrict__ out) {
  const int b = (int)blockIdx.x, t = (int)threadIdx.x;
  const int n = t >> 3, ep = t & 7;
  const __half* ph = part + ((size_t)b * kN + n) * kE + ep * 2;
  constexpr size_t slab = (size_t)kB * kN * kE;   // halves per chunk-slab
  float ax = 0.f, ay = 0.f;
#pragma unroll 4
  for (int ch = 0; ch < kNC3; ++ch) {
    const float2 f = __half22float2(*reinterpret_cast<const __half2*>(ph + (size_t)ch * slab));
    ax += f.x; ay += f.y;
  }
  float s2 = ax * ax + ay * ay;
  s2 += __shfl_xor(s2, 1, 64);
  s2 += __shfl_xor(s2, 2, 64);
  s2 += __shfl_xor(s2, 4, 64);
  const float sc = (s2 / (1.f + s2)) * rsqrtf(fmaxf(s2, 1e-30f));
  float vx = ax * sc, vy = ay * sc;
  const size_t o = ((size_t)b * kN + n) * kE + ep * 2;
  if (MODE == 2) {
    *reinterpret_cast<float2*>(out + o) = make_float2(vx, vy);
  } else {
    if (MODE == 1) {
      const float2 old = *reinterpret_cast<const float2*>(vsum + o);
      vx += old.x; vy += old.y;
    }
    *reinterpret_cast<float2*>(vsum + o) = make_float2(vx, vy);
    *reinterpret_cast<__half2*>(vsh + o) = __floats2half2_rn(vx, vy);
  }
}

}  // namespace

extern "C" void kernel_launch(void* const* d_in, const int* in_sizes, int n_in,
                              void* d_out, int out_size, void* d_ws, size_t ws_size,
                              hipStream_t stream) {
  (void)in_sizes; (void)n_in; (void)out_size; (void)ws_size;
  const float* x    = reinterpret_cast<const float*>(d_in[0]);
  const float* W    = reinterpret_cast<const float*>(d_in[1]);
  const float* bias = reinterpret_cast<const float*>(d_in[2]);
  float* out = reinterpret_cast<float*>(d_out);

  char* ws = reinterpret_cast<char*>(d_ws);
  float*   lgf  = reinterpret_cast<float*>(ws);                    // region A (f32 view)
  __half*  part = reinterpret_cast<__half*>(ws);                   // region A (fp16 view)
  __half*  c    = reinterpret_cast<__half*>(ws + kABytes);
  __half2* Whh2 = reinterpret_cast<__half2*>(ws + kABytes + kCBytes);
  int4*    Wh4  = reinterpret_cast<int4*>(Whh2);
  int4*    xh4  = reinterpret_cast<int4*>(ws + kABytes + kCBytes + kWhBytes);
  float*   vsum = reinterpret_cast<float*>(ws + kABytes + kCBytes + kWhBytes + kXhBytes);
  __half*  vsh  = reinterpret_cast<__half*>(ws + kABytes + kCBytes + kWhBytes + kXhBytes + kVsumBytes);

  const dim3 g1(kNC1, 4), g3(kNC3, 4), g2(6, kB);

  // one-time precision/layout conversion
  k0_w<<<4608, 256, 0, stream>>>(W, Whh2);
  k0_x<<<576, 256, 0, stream>>>(x, xh4);

  // iter 0: c = softmax(bias) (per (b,i) redundant but uniform); v0
  k2_softmax<0><<<g2, 192, 0, stream>>>(lgf, bias, c);
  k3_accum<<<g3, 256, 0, stream>>>(Wh4, xh4, c, part);
  k4_reduce<0><<<kB, 256, 0, stream>>>(part, vsum, vsh, out);

  // iter 1: lg = <u_hat, v0>; c = softmax(bias+lg); v1; vsh = v0+v1
  k1_logit<<<g1, 256, 0, stream>>>(Wh4, xh4, vsh, lgf);
  k2_softmax<1><<<g2, 192, 0, stream>>>(lgf, bias, c);
  k3_accum<<<g3, 256, 0, stream>>>(Wh4, xh4, c, part);
  k4_reduce<1><<<kB, 256, 0, stream>>>(part, vsum, vsh, out);

  // iter 2: lg = <u_hat, v0+v1>; out = squash(s)
  k1_logit<<<g1, 256, 0, stream>>>(Wh4, xh4, vsh, lgf);
  k2_softmax<1><<<g2, 192, 0, stream>>>(lgf, bias, c);
  k3_accum<<<g3, 256, 0, stream>>>(Wh4, xh4, c, part);
  k4_reduce<2><<<kB, 256, 0, stream>>>(part, vsum, vsh, out);
}